// Round 4
// baseline (250.463 us; speedup 1.0000x reference)
//
#include <hip/hip_runtime.h>

// out = A @ x, A sparse COO (rows, cols, edge_vals), x [N,64] f32.
// Counting-sort edges into 8-row buckets (12.5K buckets -> scatter tail-lines
// fit per-XCD L2 -> write combining works, unlike 100K-bucket sort whose
// WRITE_SIZE was exactly E*64B). Then one block per bucket: LDS-stage the
// bucket's edges coalesced, each wave owns 2 rows, row-match scan + coalesced
// gather + register accumulate + single coalesced store. No output atomics.

#define D_FEAT 64
#define ROWS_PER_BUCKET 8      // 3 bits packed into pair.x bits [25:27]
#define CHUNK 512              // LDS staging chunk (4 KB)

// ---------------- fallback (round-1 kernel) ----------------
__global__ void spmv_coo_kernel(const float* __restrict__ x,
                                const int* __restrict__ rows,
                                const int* __restrict__ cols,
                                const float* __restrict__ ev,
                                float* __restrict__ out,
                                int n_edges) {
    const int lane = threadIdx.x & 63;
    const int wave_global = blockIdx.x * (blockDim.x >> 6) + (threadIdx.x >> 6);
    const int n_waves = gridDim.x * (blockDim.x >> 6);
    for (int e = wave_global; e < n_edges; e += n_waves) {
        atomicAdd(&out[rows[e] * D_FEAT + lane], ev[e] * x[cols[e] * D_FEAT + lane]);
    }
}

// ---------------- phase 1: bucket histogram ----------------
__global__ void hist_kernel(const int* __restrict__ rows, int* __restrict__ counts,
                            int n_edges) {
    int gid = blockIdx.x * blockDim.x + threadIdx.x;
    int stride = gridDim.x * blockDim.x;
    for (int e = gid; e < n_edges; e += stride)
        atomicAdd(&counts[rows[e] >> 3], 1);
}

// ---------------- phase 2: scan ----------------
__global__ void scan_block_kernel(const int* __restrict__ counts,
                                  int* __restrict__ offsets,
                                  int* __restrict__ blocksums, int n) {
    __shared__ int s[256];
    int t = threadIdx.x;
    int gid = blockIdx.x * 256 + t;
    int val = (gid < n) ? counts[gid] : 0;
    s[t] = val;
    __syncthreads();
    for (int off = 1; off < 256; off <<= 1) {
        int tmp = (t >= off) ? s[t - off] : 0;
        __syncthreads();
        s[t] += tmp;
        __syncthreads();
    }
    if (gid < n) offsets[gid] = s[t] - val;   // exclusive within block
    if (t == 0) blocksums[blockIdx.x] = s[255];
}

__global__ void scan_tops_kernel(int* __restrict__ blocksums, int nblk) {
    __shared__ int s[512];
    int t = threadIdx.x;
    int val = (t < nblk) ? blocksums[t] : 0;
    s[t] = val;
    __syncthreads();
    for (int off = 1; off < 512; off <<= 1) {
        int tmp = (t >= off) ? s[t - off] : 0;
        __syncthreads();
        s[t] += tmp;
        __syncthreads();
    }
    if (t < nblk) blocksums[t] = s[t] - val;  // exclusive
}

__global__ void scan_add_kernel(int* __restrict__ offsets,
                                const int* __restrict__ blocksums,
                                int* __restrict__ cursor, int n, int n_edges) {
    int gid = blockIdx.x * 256 + threadIdx.x;
    if (gid < n) {
        int v = offsets[gid] + blocksums[gid >> 8];
        offsets[gid] = v;
        cursor[gid] = v;
    }
    if (gid == 0) offsets[n] = n_edges;
}

// ---------------- phase 3: scatter into bucket-sorted order ----------------
__global__ void scatter_kernel(const int* __restrict__ rows,
                               const int* __restrict__ cols,
                               const float* __restrict__ ev,
                               int* __restrict__ cursor,
                               uint2* __restrict__ pairs, int n_edges) {
    int gid = blockIdx.x * blockDim.x + threadIdx.x;
    int stride = gridDim.x * blockDim.x;
    for (int e = gid; e < n_edges; e += stride) {
        int r = rows[e];
        int pos = atomicAdd(&cursor[r >> 3], 1);
        uint2 p;
        p.x = (unsigned)cols[e] | ((unsigned)(r & 7) << 25);  // col < 2^25
        p.y = __float_as_uint(ev[e]);
        pairs[pos] = p;
    }
}

// ---------------- phase 4: per-bucket reduction ----------------
// One 256-thread block per bucket (8 rows). Wave w owns rows {2w, 2w+1}.
// Stage bucket edges to LDS coalesced; every wave scans the chunk with
// broadcast LDS reads (wave-uniform row-match branch, ~25% taken).
__global__ void __launch_bounds__(256) bucket_reduce_kernel(
        const float* __restrict__ x,
        const int* __restrict__ offsets,
        const uint2* __restrict__ pairs,
        float* __restrict__ out, int n_rows) {
    __shared__ uint2 buf[CHUNK];
    const int tid = threadIdx.x;
    const int lane = tid & 63;
    const int w = tid >> 6;                 // 0..3
    const int b = blockIdx.x;
    const int s = offsets[b];
    const int e = offsets[b + 1];
    float acc0 = 0.0f, acc1 = 0.0f;
    for (int base = s; base < e; base += CHUNK) {
        const int cnt = min(CHUNK, e - base);
        __syncthreads();
        for (int i = tid; i < cnt; i += 256) buf[i] = pairs[base + i];
        __syncthreads();
        for (int i = 0; i < cnt; ++i) {
            const uint2 p = buf[i];          // broadcast LDS read
            const int r3 = (int)(p.x >> 25);
            if ((r3 >> 1) == w) {            // wave-uniform branch
                const int c = (int)(p.x & 0x01FFFFFFu);
                const float m = __uint_as_float(p.y) * x[c * D_FEAT + lane];
                if (r3 & 1) acc1 += m; else acc0 += m;
            }
        }
    }
    const int row0 = b * ROWS_PER_BUCKET + w * 2;
    if (row0 < n_rows)     out[row0 * D_FEAT + lane]       = acc0;
    if (row0 + 1 < n_rows) out[(row0 + 1) * D_FEAT + lane] = acc1;
}

extern "C" void kernel_launch(void* const* d_in, const int* in_sizes, int n_in,
                              void* d_out, int out_size, void* d_ws, size_t ws_size,
                              hipStream_t stream) {
    const float* x    = (const float*)d_in[1];
    const int*   rows = (const int*)d_in[2];
    const int*   cols = (const int*)d_in[3];
    const float* ev   = (const float*)d_in[4];
    float* out = (float*)d_out;
    const int n_edges = in_sizes[3];
    const int n_rows  = out_size / D_FEAT;
    const int n_buckets = (n_rows + ROWS_PER_BUCKET - 1) / ROWS_PER_BUCKET;

    // workspace layout (bytes)
    size_t off_counts  = 0;
    size_t off_offsets = off_counts + (size_t)n_buckets * 4;
    size_t off_cursor  = off_offsets + ((size_t)n_buckets + 2) * 4;
    const int nblk = (n_buckets + 255) / 256;       // 49 for N=100K
    size_t off_bsums   = off_cursor + (size_t)n_buckets * 4;
    size_t off_pairs   = (off_bsums + (size_t)nblk * 4 + 7) & ~(size_t)7;
    size_t need = off_pairs + (size_t)n_edges * 8;

    if (ws_size < need || nblk > 512) {
        hipMemsetAsync(d_out, 0, (size_t)out_size * sizeof(float), stream);
        spmv_coo_kernel<<<4096, 256, 0, stream>>>(x, rows, cols, ev, out, n_edges);
        return;
    }

    char* ws = (char*)d_ws;
    int*   counts  = (int*)(ws + off_counts);
    int*   offsets = (int*)(ws + off_offsets);
    int*   cursor  = (int*)(ws + off_cursor);
    int*   bsums   = (int*)(ws + off_bsums);
    uint2* pairs   = (uint2*)(ws + off_pairs);

    hipMemsetAsync(counts, 0, (size_t)n_buckets * 4, stream);

    const int block = 256;
    const int gs_grid = 2048;

    hist_kernel<<<gs_grid, block, 0, stream>>>(rows, counts, n_edges);
    scan_block_kernel<<<nblk, 256, 0, stream>>>(counts, offsets, bsums, n_buckets);
    scan_tops_kernel<<<1, 512, 0, stream>>>(bsums, nblk);
    scan_add_kernel<<<nblk, 256, 0, stream>>>(offsets, bsums, cursor, n_buckets, n_edges);
    scatter_kernel<<<gs_grid, block, 0, stream>>>(rows, cols, ev, cursor, pairs, n_edges);

    bucket_reduce_kernel<<<n_buckets, 256, 0, stream>>>(x, offsets, pairs, out, n_rows);
}